// Round 10
// baseline (376.078 us; speedup 1.0000x reference)
//
#include <hip/hip_runtime.h>
#include <hip/hip_bf16.h>

typedef __attribute__((ext_vector_type(8))) short bf16x8;
typedef __attribute__((ext_vector_type(4))) float f32x4;

#define NB 2048      // batch
#define ND 1280      // per-stream dim
#define NK 5120      // 4*ND
#define NE 512       // EMBED

static __device__ inline unsigned short f2bf(float x) {
    union { float f; unsigned u; } c; c.f = x;
    unsigned r = c.u + 0x7FFFu + ((c.u >> 16) & 1u);
    return (unsigned short)(r >> 16);
}

// ---------------------------------------------------------------------------
// Kernel 1: fused masked-mean over T -> feat bf16 [B][4D].
// Wave-per-row layout: block = 4 consecutive b-rows (one per wave); lane l
// owns float4-chunks l+64j (j=0..4) of its row. A/B vs round 9: PLAIN loads
// (nontemporal removed) -- NT cache-bypass suspected of ~25% stream-BW loss.
// blocks [0,2048): reduce (segs ordered 1,3,0,2 for tail-packing).
// blocks [2048,4608): W1 transpose->bf16 (+zero s1s2).
// ---------------------------------------------------------------------------
__global__ __launch_bounds__(256) void reduce_w1t_kernel(
    const f32x4* __restrict__ q, const f32x4* __restrict__ vq,
    const f32x4* __restrict__ aa, const f32x4* __restrict__ va,
    const int* __restrict__ qlen, const int* __restrict__ alen,
    ushort4* __restrict__ feat,
    const float* __restrict__ W1, unsigned short* __restrict__ w1t,
    float* __restrict__ s1s2)
{
    __shared__ unsigned short lds[32][33];

    if (blockIdx.x >= 2048) {
        // ---- W1 transpose path ----
        const int bid = blockIdx.x - 2048;
        if (bid == 0) {
            ((f32x4*)s1s2)[threadIdx.x] = (f32x4){0.f, 0.f, 0.f, 0.f};
        }
        const int kb = (bid >> 4) * 32;
        const int nb = (bid & 15) * 32;
        const int tx = threadIdx.x & 31;
        const int ty = threadIdx.x >> 5;   // 0..7
        #pragma unroll
        for (int i = 0; i < 4; ++i) {
            int k = kb + ty + i * 8;
            lds[ty + i * 8][tx] = f2bf(W1[(long)k * NE + nb + tx]);
        }
        __syncthreads();
        #pragma unroll
        for (int i = 0; i < 4; ++i) {
            int n = nb + ty + i * 8;
            w1t[(long)n * NK + kb + tx] = lds[tx][ty + i * 8];
        }
        return;
    }

    // ---- masked-mean path (seg order: 1,3,0,2) ----
    const int blk = blockIdx.x;
    const int sb = blk >> 9;                    // 0..3
    const int seg = (sb == 0) ? 1 : (sb == 1) ? 3 : (sb == 2) ? 0 : 2;
    const int rb = blk & 511;
    const int wv = threadIdx.x >> 6;            // 0..3 -> row within block
    const int lane = threadIdx.x & 63;
    const int b = rb * 4 + wv;

    const long rowbase = (long)b * 320 + lane;  // float4 units
    const long stride = (long)NB * 320;         // one t-plane

    f32x4 a0 = {0.f,0.f,0.f,0.f}, a1 = {0.f,0.f,0.f,0.f}, a2 = {0.f,0.f,0.f,0.f},
          a3 = {0.f,0.f,0.f,0.f}, a4 = {0.f,0.f,0.f,0.f};
    float inv;

    if (seg == 1 || seg == 3) {
        const f32x4* src = (seg == 1) ? vq : va;
        #pragma unroll 4
        for (int t = 0; t < 64; ++t) {
            const f32x4* p = src + rowbase + (long)t * stride;
            a0 += p[0];
            a1 += p[64];
            a2 += p[128];
            a3 += p[192];
            a4 += p[256];
        }
        inv = 1.0f / 64.0f;
    } else {
        const f32x4* src = (seg == 0) ? q : aa;
        const int len = (seg == 0) ? qlen[b] : alen[b];   // wave-uniform
        #pragma unroll 2
        for (int t = 0; t < len; ++t) {
            const f32x4* p = src + rowbase + (long)t * stride;
            a0 += p[0];
            a1 += p[64];
            a2 += p[128];
            a3 += p[192];
            a4 += p[256];
        }
        inv = 1.0f / (float)len;
    }

    const long fb = (long)b * (NK / 4) + seg * 320 + lane;
    ushort4 o;
    o.x = f2bf(a0.x * inv); o.y = f2bf(a0.y * inv);
    o.z = f2bf(a0.z * inv); o.w = f2bf(a0.w * inv);
    feat[fb] = o;
    o.x = f2bf(a1.x * inv); o.y = f2bf(a1.y * inv);
    o.z = f2bf(a1.z * inv); o.w = f2bf(a1.w * inv);
    feat[fb + 64] = o;
    o.x = f2bf(a2.x * inv); o.y = f2bf(a2.y * inv);
    o.z = f2bf(a2.z * inv); o.w = f2bf(a2.w * inv);
    feat[fb + 128] = o;
    o.x = f2bf(a3.x * inv); o.y = f2bf(a3.y * inv);
    o.z = f2bf(a3.z * inv); o.w = f2bf(a3.w * inv);
    feat[fb + 192] = o;
    o.x = f2bf(a4.x * inv); o.y = f2bf(a4.y * inv);
    o.z = f2bf(a4.z * inv); o.w = f2bf(a4.w * inv);
    feat[fb + 256] = o;
}

// ---------------------------------------------------------------------------
// Kernel 2: bf16 MFMA GEMM, tiles 64x64, wave=32x32 (acc[2][2]), K=5120,
// grid 256 blocks (1/CU), XCD-aware mapping (m = bid&31).
// LDS double-buffer + prefetch depth 2 (two named reg sets, statically
// unrolled x2); one barrier per sub-step. Fused bias/ELU/store/BN epilogue.
// ---------------------------------------------------------------------------
__global__ __launch_bounds__(256) void gemm_kernel(
    const unsigned short* __restrict__ feat, const unsigned short* __restrict__ w1t,
    const float* __restrict__ b1,
    float* __restrict__ h, float* __restrict__ s1s2)
{
    __shared__ int4 As[2][64 * 9];   // 2 x 64 rows x 144B (16B pad)
    __shared__ int4 Bs[2][64 * 9];

    const int bid = blockIdx.x;
    const int m0 = (bid & 31) << 6;         // m-tile fastest -> same-m on same XCD
    const int n0 = (bid >> 5) << 6;         // 0..448

    const int t = threadIdx.x;
    const int l = t & 63;
    const int w = t >> 6;
    const int wm = (w >> 1) << 5;           // 0 or 32
    const int wn = (w & 1) << 5;            // 0 or 32
    const int srow = t >> 2;                // 0..63
    const int sc = (t & 3) << 1;            // 16B-chunk 0,2,4,6

    const unsigned short* Ab = feat + (long)(m0 + srow) * NK + sc * 8;
    const unsigned short* Bb = w1t + (long)(n0 + srow) * NK + sc * 8;

    f32x4 acc[2][2] = {};

    // prefetch set 0 (k-step k0) and set 1 (k-step k0+64)
    int4 pa0_0 = *(const int4*)(Ab);
    int4 pa1_0 = *(const int4*)(Ab + 8);
    int4 pb0_0 = *(const int4*)(Bb);
    int4 pb1_0 = *(const int4*)(Bb + 8);
    int4 pa0_1 = *(const int4*)(Ab + 64);
    int4 pa1_1 = *(const int4*)(Ab + 72);
    int4 pb0_1 = *(const int4*)(Bb + 64);
    int4 pb1_1 = *(const int4*)(Bb + 72);

    #pragma unroll 1
    for (int k0 = 0; k0 < NK; k0 += 128) {
        // ---------- even sub-step: set0 -> buffer 0 ----------
        As[0][srow * 9 + sc] = pa0_0;
        As[0][srow * 9 + sc + 1] = pa1_0;
        Bs[0][srow * 9 + sc] = pb0_0;
        Bs[0][srow * 9 + sc + 1] = pb1_0;
        if (k0 + 128 < NK) {
            pa0_0 = *(const int4*)(Ab + k0 + 128);
            pa1_0 = *(const int4*)(Ab + k0 + 136);
            pb0_0 = *(const int4*)(Bb + k0 + 128);
            pb1_0 = *(const int4*)(Bb + k0 + 136);
        }
        __syncthreads();
        #pragma unroll
        for (int kk = 0; kk < 2; ++kk) {
            const int kc = kk * 4 + (l >> 4);
            bf16x8 af0 = *(const bf16x8*)&As[0][(wm + (l & 15)) * 9 + kc];
            bf16x8 af1 = *(const bf16x8*)&As[0][(wm + 16 + (l & 15)) * 9 + kc];
            bf16x8 bf0 = *(const bf16x8*)&Bs[0][(wn + (l & 15)) * 9 + kc];
            bf16x8 bf1 = *(const bf16x8*)&Bs[0][(wn + 16 + (l & 15)) * 9 + kc];
            acc[0][0] = __builtin_amdgcn_mfma_f32_16x16x32_bf16(af0, bf0, acc[0][0], 0, 0, 0);
            acc[0][1] = __builtin_amdgcn_mfma_f32_16x16x32_bf16(af0, bf1, acc[0][1], 0, 0, 0);
            acc[1][0] = __builtin_amdgcn_mfma_f32_16x16x32_bf16(af1, bf0, acc[1][0], 0, 0, 0);
            acc[1][1] = __builtin_amdgcn_mfma_f32_16x16x32_bf16(af1, bf1, acc[1][1], 0, 0, 0);
        }
        // ---------- odd sub-step: set1 -> buffer 1 ----------
        As[1][srow * 9 + sc] = pa0_1;
        As[1][srow * 9 + sc + 1] = pa1_1;
        Bs[1][srow * 9 + sc] = pb0_1;
        Bs[1][srow * 9 + sc + 1] = pb1_1;
        if (k0 + 192 < NK) {
            pa0_1 = *(const int4*)(Ab + k0 + 192);
            pa1_1 = *(const int4*)(Ab + k0 + 200);
            pb0_1 = *(const int4*)(Bb + k0 + 192);
            pb1_1 = *(const int4*)(Bb + k0 + 200);
        }
        __syncthreads();
        #pragma unroll
        for (int kk = 0; kk < 2; ++kk) {
            const int kc = kk * 4 + (l >> 4);
            bf16x8 af0 = *(const bf16x8*)&As[1][(wm + (l & 15)) * 9 + kc];
            bf16x8 af1 = *(const bf16x8*)&As[1][(wm + 16 + (l & 15)) * 9 + kc];
            bf16x8 bf0 = *(const bf16x8*)&Bs[1][(wn + (l & 15)) * 9 + kc];
            bf16x8 bf1 = *(const bf16x8*)&Bs[1][(wn + 16 + (l & 15)) * 9 + kc];
            acc[0][0] = __builtin_amdgcn_mfma_f32_16x16x32_bf16(af0, bf0, acc[0][0], 0, 0, 0);
            acc[0][1] = __builtin_amdgcn_mfma_f32_16x16x32_bf16(af0, bf1, acc[0][1], 0, 0, 0);
            acc[1][0] = __builtin_amdgcn_mfma_f32_16x16x32_bf16(af1, bf0, acc[1][0], 0, 0, 0);
            acc[1][1] = __builtin_amdgcn_mfma_f32_16x16x32_bf16(af1, bf1, acc[1][1], 0, 0, 0);
        }
    }

    // epilogue: bias + ELU + store + column stats
    const int r0 = m0 + wm + ((l >> 4) << 2);
    #pragma unroll
    for (int ni = 0; ni < 2; ++ni) {
        const int col = n0 + wn + ni * 16 + (l & 15);
        const float bias = b1[col];
        float s1 = 0.f, s2 = 0.f;
        #pragma unroll
        for (int mi = 0; mi < 2; ++mi) {
            #pragma unroll
            for (int rr = 0; rr < 4; ++rr) {
                float v = acc[mi][ni][rr] + bias;
                v = v > 0.f ? v : expm1f(v);
                h[(long)(r0 + mi * 16 + rr) * NE + col] = v;
                s1 += v; s2 += v * v;
            }
        }
        // lanes l, l^16, l^32, l^48 share col; reduce 32 rows of this wave
        s1 += __shfl_xor(s1, 16); s2 += __shfl_xor(s2, 16);
        s1 += __shfl_xor(s1, 32); s2 += __shfl_xor(s2, 32);
        if (l < 16) {
            unsafeAtomicAdd(&s1s2[col], s1);
            unsafeAtomicAdd(&s1s2[NE + col], s2);
        }
    }
}

// ---------------------------------------------------------------------------
// Kernel 3: fused finalize + output. Each block recomputes the folded BN/W2
// coefficients (4 KB read, L2-hot) then does 4 rows of the 512-dot product.
// ---------------------------------------------------------------------------
__global__ __launch_bounds__(256) void out_kernel(
    const float* __restrict__ h, const float* __restrict__ s1s2,
    const float* __restrict__ gamma, const float* __restrict__ beta,
    const float* __restrict__ W2, const float* __restrict__ b2,
    float* __restrict__ out)
{
    __shared__ float coef[NE];
    __shared__ float red[256];
    const int t = threadIdx.x;

    float term = 0.f;
    #pragma unroll
    for (int i = 0; i < 2; ++i) {
        const int e = t + i * 256;
        const float s1 = s1s2[e];
        const float s2 = s1s2[NE + e];
        const float mu = s1 * (1.0f / NB);
        const float var = s2 * (1.0f / NB) - mu * mu;
        const float rs = rsqrtf(var + 1e-5f);
        const float g = gamma[e], wv = W2[e];
        coef[e] = rs * g * wv;
        term += (beta[e] - mu * rs * g) * wv;
    }
    red[t] = term;
    __syncthreads();
    #pragma unroll
    for (int off = 128; off > 0; off >>= 1) {
        if (t < off) red[t] += red[t + off];
        __syncthreads();
    }
    const float cst = red[0] + b2[0];

    const int w = t >> 6;
    const int l = t & 63;
    const int row = blockIdx.x * 4 + w;
    const f32x4* h4 = (const f32x4*)(h + (long)row * NE);
    f32x4 x0 = h4[l * 2], x1 = h4[l * 2 + 1];
    f32x4 c0 = *(const f32x4*)&coef[l * 8];
    f32x4 c1 = *(const f32x4*)&coef[l * 8 + 4];
    float dot = x0.x * c0.x + x0.y * c0.y + x0.z * c0.z + x0.w * c0.w
              + x1.x * c1.x + x1.y * c1.y + x1.z * c1.z + x1.w * c1.w;
    #pragma unroll
    for (int off = 32; off > 0; off >>= 1) dot += __shfl_down(dot, off);
    if (l == 0) out[row] = dot + cst;
}

// ---------------------------------------------------------------------------
extern "C" void kernel_launch(void* const* d_in, const int* in_sizes, int n_in,
                              void* d_out, int out_size, void* d_ws, size_t ws_size,
                              hipStream_t stream)
{
    const float* q    = (const float*)d_in[0];
    const float* vq   = (const float*)d_in[1];
    const float* aa   = (const float*)d_in[2];
    const float* va   = (const float*)d_in[3];
    const float* W1   = (const float*)d_in[4];
    const float* b1   = (const float*)d_in[5];
    const float* gam  = (const float*)d_in[6];
    const float* bet  = (const float*)d_in[7];
    const float* W2   = (const float*)d_in[8];
    const float* b2   = (const float*)d_in[9];
    const int* qlen   = (const int*)d_in[10];
    const int* alen   = (const int*)d_in[11];
    float* out = (float*)d_out;

    char* ws = (char*)d_ws;
    unsigned short* feat = (unsigned short*)ws;                 // 20,971,520 B
    unsigned short* w1t  = (unsigned short*)(ws + 20971520);    //  5,242,880 B
    float* hbuf          = (float*)(ws + 26214400);             //  4,194,304 B
    float* s1s2          = (float*)(ws + 30408704);             //      4,096 B

    reduce_w1t_kernel<<<4608, 256, 0, stream>>>(
        (const f32x4*)q, (const f32x4*)vq, (const f32x4*)aa, (const f32x4*)va,
        qlen, alen, (ushort4*)feat, W1, w1t, s1s2);

    gemm_kernel<<<256, 256, 0, stream>>>(feat, w1t, b1, hbuf, s1s2);

    out_kernel<<<512, 256, 0, stream>>>(hbuf, s1s2, gam, bet, W2, b2, out);
}

// Round 11
// 335.452 us; speedup vs baseline: 1.1211x; 1.1211x over previous
//
#include <hip/hip_runtime.h>
#include <hip/hip_bf16.h>

typedef __attribute__((ext_vector_type(8))) short bf16x8;
typedef __attribute__((ext_vector_type(4))) float f32x4;

#define NB 2048      // batch
#define ND 1280      // per-stream dim
#define NK 5120      // 4*ND
#define NE 512       // EMBED

static __device__ inline unsigned short f2bf(float x) {
    union { float f; unsigned u; } c; c.f = x;
    unsigned r = c.u + 0x7FFFu + ((c.u >> 16) & 1u);
    return (unsigned short)(r >> 16);
}

// ---------------------------------------------------------------------------
// Kernel 1: fused masked-mean over T -> feat bf16 [B][4D].
// Wave-per-row: block = 4 consecutive b-rows (one per wave); lane l owns
// float4-chunks l+64j (j=0..4). NT loads (A/B round 9 vs 10: NT is +38 us).
// v2: explicit 2-deep register pipeline -- plane t+1's 5 loads issue BEFORE
// plane t's accumulate, keeping >=10 loads in flight per wave continuously
// (round-8 PMC: VALUBusy 2.5%, occ 64% -> iteration-boundary latency bubble
// was the remaining suspect).
// blocks [0,2048): reduce (segs ordered 1,3,0,2 for tail-packing).
// blocks [2048,4608): W1 transpose->bf16 (+zero s1s2).
// ---------------------------------------------------------------------------
__global__ __launch_bounds__(256) void reduce_w1t_kernel(
    const f32x4* __restrict__ q, const f32x4* __restrict__ vq,
    const f32x4* __restrict__ aa, const f32x4* __restrict__ va,
    const int* __restrict__ qlen, const int* __restrict__ alen,
    ushort4* __restrict__ feat,
    const float* __restrict__ W1, unsigned short* __restrict__ w1t,
    float* __restrict__ s1s2)
{
    __shared__ unsigned short lds[32][33];

    if (blockIdx.x >= 2048) {
        // ---- W1 transpose path ----
        const int bid = blockIdx.x - 2048;
        if (bid == 0) {
            ((f32x4*)s1s2)[threadIdx.x] = (f32x4){0.f, 0.f, 0.f, 0.f};
        }
        const int kb = (bid >> 4) * 32;
        const int nb = (bid & 15) * 32;
        const int tx = threadIdx.x & 31;
        const int ty = threadIdx.x >> 5;   // 0..7
        #pragma unroll
        for (int i = 0; i < 4; ++i) {
            int k = kb + ty + i * 8;
            lds[ty + i * 8][tx] = f2bf(W1[(long)k * NE + nb + tx]);
        }
        __syncthreads();
        #pragma unroll
        for (int i = 0; i < 4; ++i) {
            int n = nb + ty + i * 8;
            w1t[(long)n * NK + kb + tx] = lds[tx][ty + i * 8];
        }
        return;
    }

    // ---- masked-mean path (seg order: 1,3,0,2) ----
    const int blk = blockIdx.x;
    const int sb = blk >> 9;                    // 0..3
    const int seg = (sb == 0) ? 1 : (sb == 1) ? 3 : (sb == 2) ? 0 : 2;
    const int rb = blk & 511;
    const int wv = threadIdx.x >> 6;            // 0..3 -> row within block
    const int lane = threadIdx.x & 63;
    const int b = rb * 4 + wv;

    const long stride = (long)NB * 320;         // one t-plane in float4s
    const long rowbase = (long)b * 320 + lane;

    const f32x4* src;
    int len;
    if (seg == 1)      { src = vq; len = 64; }
    else if (seg == 3) { src = va; len = 64; }
    else if (seg == 0) { src = q;  len = qlen[b]; }   // wave-uniform
    else               { src = aa; len = alen[b]; }

    f32x4 a0 = {0.f,0.f,0.f,0.f}, a1 = {0.f,0.f,0.f,0.f}, a2 = {0.f,0.f,0.f,0.f},
          a3 = {0.f,0.f,0.f,0.f}, a4 = {0.f,0.f,0.f,0.f};

    const f32x4* p = src + rowbase;
    f32x4 v0 = __builtin_nontemporal_load(&p[0]);
    f32x4 v1 = __builtin_nontemporal_load(&p[64]);
    f32x4 v2 = __builtin_nontemporal_load(&p[128]);
    f32x4 v3 = __builtin_nontemporal_load(&p[192]);
    f32x4 v4 = __builtin_nontemporal_load(&p[256]);

    #pragma unroll 2
    for (int t = 0; t < len; ++t) {
        const int tn = (t + 1 < len) ? (t + 1) : t;   // branchless tail reload (L1-hot)
        const f32x4* pn = src + rowbase + (long)tn * stride;
        f32x4 u0 = __builtin_nontemporal_load(&pn[0]);
        f32x4 u1 = __builtin_nontemporal_load(&pn[64]);
        f32x4 u2 = __builtin_nontemporal_load(&pn[128]);
        f32x4 u3 = __builtin_nontemporal_load(&pn[192]);
        f32x4 u4 = __builtin_nontemporal_load(&pn[256]);
        a0 += v0; a1 += v1; a2 += v2; a3 += v3; a4 += v4;
        v0 = u0; v1 = u1; v2 = u2; v3 = u3; v4 = u4;
    }
    const float inv = 1.0f / (float)len;

    const long fb = (long)b * (NK / 4) + seg * 320 + lane;
    ushort4 o;
    o.x = f2bf(a0.x * inv); o.y = f2bf(a0.y * inv);
    o.z = f2bf(a0.z * inv); o.w = f2bf(a0.w * inv);
    feat[fb] = o;
    o.x = f2bf(a1.x * inv); o.y = f2bf(a1.y * inv);
    o.z = f2bf(a1.z * inv); o.w = f2bf(a1.w * inv);
    feat[fb + 64] = o;
    o.x = f2bf(a2.x * inv); o.y = f2bf(a2.y * inv);
    o.z = f2bf(a2.z * inv); o.w = f2bf(a2.w * inv);
    feat[fb + 128] = o;
    o.x = f2bf(a3.x * inv); o.y = f2bf(a3.y * inv);
    o.z = f2bf(a3.z * inv); o.w = f2bf(a3.w * inv);
    feat[fb + 192] = o;
    o.x = f2bf(a4.x * inv); o.y = f2bf(a4.y * inv);
    o.z = f2bf(a4.z * inv); o.w = f2bf(a4.w * inv);
    feat[fb + 256] = o;
}

// ---------------------------------------------------------------------------
// Kernel 2: bf16 MFMA GEMM, tiles 64x64, wave=32x32 (acc[2][2]), K=5120,
// grid 256 blocks (1/CU), XCD-aware mapping (m = bid&31).
// LDS double-buffer + prefetch depth 2 (two named reg sets, statically
// unrolled x2); one barrier per sub-step. Fused bias/ELU/store/BN epilogue.
// ---------------------------------------------------------------------------
__global__ __launch_bounds__(256) void gemm_kernel(
    const unsigned short* __restrict__ feat, const unsigned short* __restrict__ w1t,
    const float* __restrict__ b1,
    float* __restrict__ h, float* __restrict__ s1s2)
{
    __shared__ int4 As[2][64 * 9];   // 2 x 64 rows x 144B (16B pad)
    __shared__ int4 Bs[2][64 * 9];

    const int bid = blockIdx.x;
    const int m0 = (bid & 31) << 6;         // m-tile fastest -> same-m on same XCD
    const int n0 = (bid >> 5) << 6;         // 0..448

    const int t = threadIdx.x;
    const int l = t & 63;
    const int w = t >> 6;
    const int wm = (w >> 1) << 5;           // 0 or 32
    const int wn = (w & 1) << 5;            // 0 or 32
    const int srow = t >> 2;                // 0..63
    const int sc = (t & 3) << 1;            // 16B-chunk 0,2,4,6

    const unsigned short* Ab = feat + (long)(m0 + srow) * NK + sc * 8;
    const unsigned short* Bb = w1t + (long)(n0 + srow) * NK + sc * 8;

    f32x4 acc[2][2] = {};

    // prefetch set 0 (k-step k0) and set 1 (k-step k0+64)
    int4 pa0_0 = *(const int4*)(Ab);
    int4 pa1_0 = *(const int4*)(Ab + 8);
    int4 pb0_0 = *(const int4*)(Bb);
    int4 pb1_0 = *(const int4*)(Bb + 8);
    int4 pa0_1 = *(const int4*)(Ab + 64);
    int4 pa1_1 = *(const int4*)(Ab + 72);
    int4 pb0_1 = *(const int4*)(Bb + 64);
    int4 pb1_1 = *(const int4*)(Bb + 72);

    #pragma unroll 1
    for (int k0 = 0; k0 < NK; k0 += 128) {
        // ---------- even sub-step: set0 -> buffer 0 ----------
        As[0][srow * 9 + sc] = pa0_0;
        As[0][srow * 9 + sc + 1] = pa1_0;
        Bs[0][srow * 9 + sc] = pb0_0;
        Bs[0][srow * 9 + sc + 1] = pb1_0;
        if (k0 + 128 < NK) {
            pa0_0 = *(const int4*)(Ab + k0 + 128);
            pa1_0 = *(const int4*)(Ab + k0 + 136);
            pb0_0 = *(const int4*)(Bb + k0 + 128);
            pb1_0 = *(const int4*)(Bb + k0 + 136);
        }
        __syncthreads();
        #pragma unroll
        for (int kk = 0; kk < 2; ++kk) {
            const int kc = kk * 4 + (l >> 4);
            bf16x8 af0 = *(const bf16x8*)&As[0][(wm + (l & 15)) * 9 + kc];
            bf16x8 af1 = *(const bf16x8*)&As[0][(wm + 16 + (l & 15)) * 9 + kc];
            bf16x8 bf0 = *(const bf16x8*)&Bs[0][(wn + (l & 15)) * 9 + kc];
            bf16x8 bf1 = *(const bf16x8*)&Bs[0][(wn + 16 + (l & 15)) * 9 + kc];
            acc[0][0] = __builtin_amdgcn_mfma_f32_16x16x32_bf16(af0, bf0, acc[0][0], 0, 0, 0);
            acc[0][1] = __builtin_amdgcn_mfma_f32_16x16x32_bf16(af0, bf1, acc[0][1], 0, 0, 0);
            acc[1][0] = __builtin_amdgcn_mfma_f32_16x16x32_bf16(af1, bf0, acc[1][0], 0, 0, 0);
            acc[1][1] = __builtin_amdgcn_mfma_f32_16x16x32_bf16(af1, bf1, acc[1][1], 0, 0, 0);
        }
        // ---------- odd sub-step: set1 -> buffer 1 ----------
        As[1][srow * 9 + sc] = pa0_1;
        As[1][srow * 9 + sc + 1] = pa1_1;
        Bs[1][srow * 9 + sc] = pb0_1;
        Bs[1][srow * 9 + sc + 1] = pb1_1;
        if (k0 + 192 < NK) {
            pa0_1 = *(const int4*)(Ab + k0 + 192);
            pa1_1 = *(const int4*)(Ab + k0 + 200);
            pb0_1 = *(const int4*)(Bb + k0 + 192);
            pb1_1 = *(const int4*)(Bb + k0 + 200);
        }
        __syncthreads();
        #pragma unroll
        for (int kk = 0; kk < 2; ++kk) {
            const int kc = kk * 4 + (l >> 4);
            bf16x8 af0 = *(const bf16x8*)&As[1][(wm + (l & 15)) * 9 + kc];
            bf16x8 af1 = *(const bf16x8*)&As[1][(wm + 16 + (l & 15)) * 9 + kc];
            bf16x8 bf0 = *(const bf16x8*)&Bs[1][(wn + (l & 15)) * 9 + kc];
            bf16x8 bf1 = *(const bf16x8*)&Bs[1][(wn + 16 + (l & 15)) * 9 + kc];
            acc[0][0] = __builtin_amdgcn_mfma_f32_16x16x32_bf16(af0, bf0, acc[0][0], 0, 0, 0);
            acc[0][1] = __builtin_amdgcn_mfma_f32_16x16x32_bf16(af0, bf1, acc[0][1], 0, 0, 0);
            acc[1][0] = __builtin_amdgcn_mfma_f32_16x16x32_bf16(af1, bf0, acc[1][0], 0, 0, 0);
            acc[1][1] = __builtin_amdgcn_mfma_f32_16x16x32_bf16(af1, bf1, acc[1][1], 0, 0, 0);
        }
    }

    // epilogue: bias + ELU + store + column stats
    const int r0 = m0 + wm + ((l >> 4) << 2);
    #pragma unroll
    for (int ni = 0; ni < 2; ++ni) {
        const int col = n0 + wn + ni * 16 + (l & 15);
        const float bias = b1[col];
        float s1 = 0.f, s2 = 0.f;
        #pragma unroll
        for (int mi = 0; mi < 2; ++mi) {
            #pragma unroll
            for (int rr = 0; rr < 4; ++rr) {
                float v = acc[mi][ni][rr] + bias;
                v = v > 0.f ? v : expm1f(v);
                h[(long)(r0 + mi * 16 + rr) * NE + col] = v;
                s1 += v; s2 += v * v;
            }
        }
        // lanes l, l^16, l^32, l^48 share col; reduce 32 rows of this wave
        s1 += __shfl_xor(s1, 16); s2 += __shfl_xor(s2, 16);
        s1 += __shfl_xor(s1, 32); s2 += __shfl_xor(s2, 32);
        if (l < 16) {
            unsafeAtomicAdd(&s1s2[col], s1);
            unsafeAtomicAdd(&s1s2[NE + col], s2);
        }
    }
}

// ---------------------------------------------------------------------------
// Kernel 3: fused finalize + output. Each block recomputes the folded BN/W2
// coefficients (4 KB read, L2-hot) then does 4 rows of the 512-dot product.
// ---------------------------------------------------------------------------
__global__ __launch_bounds__(256) void out_kernel(
    const float* __restrict__ h, const float* __restrict__ s1s2,
    const float* __restrict__ gamma, const float* __restrict__ beta,
    const float* __restrict__ W2, const float* __restrict__ b2,
    float* __restrict__ out)
{
    __shared__ float coef[NE];
    __shared__ float red[256];
    const int t = threadIdx.x;

    float term = 0.f;
    #pragma unroll
    for (int i = 0; i < 2; ++i) {
        const int e = t + i * 256;
        const float s1 = s1s2[e];
        const float s2 = s1s2[NE + e];
        const float mu = s1 * (1.0f / NB);
        const float var = s2 * (1.0f / NB) - mu * mu;
        const float rs = rsqrtf(var + 1e-5f);
        const float g = gamma[e], wv = W2[e];
        coef[e] = rs * g * wv;
        term += (beta[e] - mu * rs * g) * wv;
    }
    red[t] = term;
    __syncthreads();
    #pragma unroll
    for (int off = 128; off > 0; off >>= 1) {
        if (t < off) red[t] += red[t + off];
        __syncthreads();
    }
    const float cst = red[0] + b2[0];

    const int w = t >> 6;
    const int l = t & 63;
    const int row = blockIdx.x * 4 + w;
    const f32x4* h4 = (const f32x4*)(h + (long)row * NE);
    f32x4 x0 = h4[l * 2], x1 = h4[l * 2 + 1];
    f32x4 c0 = *(const f32x4*)&coef[l * 8];
    f32x4 c1 = *(const f32x4*)&coef[l * 8 + 4];
    float dot = x0.x * c0.x + x0.y * c0.y + x0.z * c0.z + x0.w * c0.w
              + x1.x * c1.x + x1.y * c1.y + x1.z * c1.z + x1.w * c1.w;
    #pragma unroll
    for (int off = 32; off > 0; off >>= 1) dot += __shfl_down(dot, off);
    if (l == 0) out[row] = dot + cst;
}

// ---------------------------------------------------------------------------
extern "C" void kernel_launch(void* const* d_in, const int* in_sizes, int n_in,
                              void* d_out, int out_size, void* d_ws, size_t ws_size,
                              hipStream_t stream)
{
    const float* q    = (const float*)d_in[0];
    const float* vq   = (const float*)d_in[1];
    const float* aa   = (const float*)d_in[2];
    const float* va   = (const float*)d_in[3];
    const float* W1   = (const float*)d_in[4];
    const float* b1   = (const float*)d_in[5];
    const float* gam  = (const float*)d_in[6];
    const float* bet  = (const float*)d_in[7];
    const float* W2   = (const float*)d_in[8];
    const float* b2   = (const float*)d_in[9];
    const int* qlen   = (const int*)d_in[10];
    const int* alen   = (const int*)d_in[11];
    float* out = (float*)d_out;

    char* ws = (char*)d_ws;
    unsigned short* feat = (unsigned short*)ws;                 // 20,971,520 B
    unsigned short* w1t  = (unsigned short*)(ws + 20971520);    //  5,242,880 B
    float* hbuf          = (float*)(ws + 26214400);             //  4,194,304 B
    float* s1s2          = (float*)(ws + 30408704);             //      4,096 B

    reduce_w1t_kernel<<<4608, 256, 0, stream>>>(
        (const f32x4*)q, (const f32x4*)vq, (const f32x4*)aa, (const f32x4*)va,
        qlen, alen, (ushort4*)feat, W1, w1t, s1s2);

    gemm_kernel<<<256, 256, 0, stream>>>(feat, w1t, b1, hbuf, s1s2);

    out_kernel<<<512, 256, 0, stream>>>(hbuf, s1s2, gam, bet, W2, b2, out);
}

// Round 12
// 333.603 us; speedup vs baseline: 1.1273x; 1.0055x over previous
//
#include <hip/hip_runtime.h>
#include <hip/hip_bf16.h>

typedef __attribute__((ext_vector_type(8))) short bf16x8;
typedef __attribute__((ext_vector_type(4))) float f32x4;

#define NB 2048      // batch
#define ND 1280      // per-stream dim
#define NK 5120      // 4*ND
#define NE 512       // EMBED

static __device__ inline unsigned short f2bf(float x) {
    union { float f; unsigned u; } c; c.f = x;
    unsigned r = c.u + 0x7FFFu + ((c.u >> 16) & 1u);
    return (unsigned short)(r >> 16);
}

// ---------------------------------------------------------------------------
// Kernel 1: fused masked-mean over T -> feat bf16 [B][4D].
// v3: 1024-thread blocks = 16 waves = 16 consecutive b-rows -> each block
// reads ONE 80 KB contiguous span per t-plane (4x longer linear runs than
// the 256-thread version; tests the run-length/read-BW hypothesis).
// Lane l of wave wv owns chunks l+64j (j=0..4) of row 16*rb+wv; len is
// wave-uniform. Simple (non-pipelined) loop keeps VGPR<=64 -> 2 blocks/CU.
// blocks [0,512): reduce (seg order 1,3,0,2). blocks [512,3072): W1T.
// ---------------------------------------------------------------------------
__global__ __launch_bounds__(1024) void reduce_w1t_kernel(
    const f32x4* __restrict__ q, const f32x4* __restrict__ vq,
    const f32x4* __restrict__ aa, const f32x4* __restrict__ va,
    const int* __restrict__ qlen, const int* __restrict__ alen,
    ushort4* __restrict__ feat,
    const float* __restrict__ W1, unsigned short* __restrict__ w1t,
    float* __restrict__ s1s2)
{
    __shared__ unsigned short lds[32][33];

    if (blockIdx.x >= 512) {
        // ---- W1 transpose path (1024 threads: 1 element each) ----
        const int bid = blockIdx.x - 512;
        if (bid == 0 && threadIdx.x < 256) {
            ((f32x4*)s1s2)[threadIdx.x] = (f32x4){0.f, 0.f, 0.f, 0.f};
        }
        const int kb = (bid >> 4) * 32;
        const int nb = (bid & 15) * 32;
        const int tx = threadIdx.x & 31;
        const int ty = threadIdx.x >> 5;   // 0..31
        lds[ty][tx] = f2bf(W1[(long)(kb + ty) * NE + nb + tx]);
        __syncthreads();
        w1t[(long)(nb + ty) * NK + kb + tx] = lds[tx][ty];
        return;
    }

    // ---- masked-mean path (seg order: 1,3,0,2) ----
    const int blk = blockIdx.x;
    const int sb = blk >> 7;                    // 0..3
    const int seg = (sb == 0) ? 1 : (sb == 1) ? 3 : (sb == 2) ? 0 : 2;
    const int rb = blk & 127;
    const int wv = threadIdx.x >> 6;            // 0..15 -> row within block
    const int lane = threadIdx.x & 63;
    const int b = rb * 16 + wv;

    const long stride = (long)NB * 320;         // one t-plane in float4s
    const long rowbase = (long)b * 320 + lane;

    const f32x4* src;
    int len;
    if (seg == 1)      { src = vq; len = 64; }
    else if (seg == 3) { src = va; len = 64; }
    else if (seg == 0) { src = q;  len = qlen[b]; }   // wave-uniform
    else               { src = aa; len = alen[b]; }

    f32x4 a0 = {0.f,0.f,0.f,0.f}, a1 = {0.f,0.f,0.f,0.f}, a2 = {0.f,0.f,0.f,0.f},
          a3 = {0.f,0.f,0.f,0.f}, a4 = {0.f,0.f,0.f,0.f};

    #pragma unroll 2
    for (int t = 0; t < len; ++t) {
        const f32x4* p = src + rowbase + (long)t * stride;
        a0 += __builtin_nontemporal_load(&p[0]);
        a1 += __builtin_nontemporal_load(&p[64]);
        a2 += __builtin_nontemporal_load(&p[128]);
        a3 += __builtin_nontemporal_load(&p[192]);
        a4 += __builtin_nontemporal_load(&p[256]);
    }
    const float inv = 1.0f / (float)len;

    const long fb = (long)b * (NK / 4) + seg * 320 + lane;
    ushort4 o;
    o.x = f2bf(a0.x * inv); o.y = f2bf(a0.y * inv);
    o.z = f2bf(a0.z * inv); o.w = f2bf(a0.w * inv);
    feat[fb] = o;
    o.x = f2bf(a1.x * inv); o.y = f2bf(a1.y * inv);
    o.z = f2bf(a1.z * inv); o.w = f2bf(a1.w * inv);
    feat[fb + 64] = o;
    o.x = f2bf(a2.x * inv); o.y = f2bf(a2.y * inv);
    o.z = f2bf(a2.z * inv); o.w = f2bf(a2.w * inv);
    feat[fb + 128] = o;
    o.x = f2bf(a3.x * inv); o.y = f2bf(a3.y * inv);
    o.z = f2bf(a3.z * inv); o.w = f2bf(a3.w * inv);
    feat[fb + 192] = o;
    o.x = f2bf(a4.x * inv); o.y = f2bf(a4.y * inv);
    o.z = f2bf(a4.z * inv); o.w = f2bf(a4.w * inv);
    feat[fb + 256] = o;
}

// ---------------------------------------------------------------------------
// Kernel 2: bf16 MFMA GEMM, tiles 64x64, wave=32x32 (acc[2][2]), K=5120,
// grid 256 blocks (1/CU), XCD-aware mapping (m = bid&31).
// LDS double-buffer + prefetch depth 2 (two named reg sets, statically
// unrolled x2); one barrier per sub-step. Fused bias/ELU/store/BN epilogue.
// ---------------------------------------------------------------------------
__global__ __launch_bounds__(256) void gemm_kernel(
    const unsigned short* __restrict__ feat, const unsigned short* __restrict__ w1t,
    const float* __restrict__ b1,
    float* __restrict__ h, float* __restrict__ s1s2)
{
    __shared__ int4 As[2][64 * 9];   // 2 x 64 rows x 144B (16B pad)
    __shared__ int4 Bs[2][64 * 9];

    const int bid = blockIdx.x;
    const int m0 = (bid & 31) << 6;         // m-tile fastest -> same-m on same XCD
    const int n0 = (bid >> 5) << 6;         // 0..448

    const int t = threadIdx.x;
    const int l = t & 63;
    const int w = t >> 6;
    const int wm = (w >> 1) << 5;           // 0 or 32
    const int wn = (w & 1) << 5;            // 0 or 32
    const int srow = t >> 2;                // 0..63
    const int sc = (t & 3) << 1;            // 16B-chunk 0,2,4,6

    const unsigned short* Ab = feat + (long)(m0 + srow) * NK + sc * 8;
    const unsigned short* Bb = w1t + (long)(n0 + srow) * NK + sc * 8;

    f32x4 acc[2][2] = {};

    // prefetch set 0 (k-step k0) and set 1 (k-step k0+64)
    int4 pa0_0 = *(const int4*)(Ab);
    int4 pa1_0 = *(const int4*)(Ab + 8);
    int4 pb0_0 = *(const int4*)(Bb);
    int4 pb1_0 = *(const int4*)(Bb + 8);
    int4 pa0_1 = *(const int4*)(Ab + 64);
    int4 pa1_1 = *(const int4*)(Ab + 72);
    int4 pb0_1 = *(const int4*)(Bb + 64);
    int4 pb1_1 = *(const int4*)(Bb + 72);

    #pragma unroll 1
    for (int k0 = 0; k0 < NK; k0 += 128) {
        // ---------- even sub-step: set0 -> buffer 0 ----------
        As[0][srow * 9 + sc] = pa0_0;
        As[0][srow * 9 + sc + 1] = pa1_0;
        Bs[0][srow * 9 + sc] = pb0_0;
        Bs[0][srow * 9 + sc + 1] = pb1_0;
        if (k0 + 128 < NK) {
            pa0_0 = *(const int4*)(Ab + k0 + 128);
            pa1_0 = *(const int4*)(Ab + k0 + 136);
            pb0_0 = *(const int4*)(Bb + k0 + 128);
            pb1_0 = *(const int4*)(Bb + k0 + 136);
        }
        __syncthreads();
        #pragma unroll
        for (int kk = 0; kk < 2; ++kk) {
            const int kc = kk * 4 + (l >> 4);
            bf16x8 af0 = *(const bf16x8*)&As[0][(wm + (l & 15)) * 9 + kc];
            bf16x8 af1 = *(const bf16x8*)&As[0][(wm + 16 + (l & 15)) * 9 + kc];
            bf16x8 bf0 = *(const bf16x8*)&Bs[0][(wn + (l & 15)) * 9 + kc];
            bf16x8 bf1 = *(const bf16x8*)&Bs[0][(wn + 16 + (l & 15)) * 9 + kc];
            acc[0][0] = __builtin_amdgcn_mfma_f32_16x16x32_bf16(af0, bf0, acc[0][0], 0, 0, 0);
            acc[0][1] = __builtin_amdgcn_mfma_f32_16x16x32_bf16(af0, bf1, acc[0][1], 0, 0, 0);
            acc[1][0] = __builtin_amdgcn_mfma_f32_16x16x32_bf16(af1, bf0, acc[1][0], 0, 0, 0);
            acc[1][1] = __builtin_amdgcn_mfma_f32_16x16x32_bf16(af1, bf1, acc[1][1], 0, 0, 0);
        }
        // ---------- odd sub-step: set1 -> buffer 1 ----------
        As[1][srow * 9 + sc] = pa0_1;
        As[1][srow * 9 + sc + 1] = pa1_1;
        Bs[1][srow * 9 + sc] = pb0_1;
        Bs[1][srow * 9 + sc + 1] = pb1_1;
        if (k0 + 192 < NK) {
            pa0_1 = *(const int4*)(Ab + k0 + 192);
            pa1_1 = *(const int4*)(Ab + k0 + 200);
            pb0_1 = *(const int4*)(Bb + k0 + 192);
            pb1_1 = *(const int4*)(Bb + k0 + 200);
        }
        __syncthreads();
        #pragma unroll
        for (int kk = 0; kk < 2; ++kk) {
            const int kc = kk * 4 + (l >> 4);
            bf16x8 af0 = *(const bf16x8*)&As[1][(wm + (l & 15)) * 9 + kc];
            bf16x8 af1 = *(const bf16x8*)&As[1][(wm + 16 + (l & 15)) * 9 + kc];
            bf16x8 bf0 = *(const bf16x8*)&Bs[1][(wn + (l & 15)) * 9 + kc];
            bf16x8 bf1 = *(const bf16x8*)&Bs[1][(wn + 16 + (l & 15)) * 9 + kc];
            acc[0][0] = __builtin_amdgcn_mfma_f32_16x16x32_bf16(af0, bf0, acc[0][0], 0, 0, 0);
            acc[0][1] = __builtin_amdgcn_mfma_f32_16x16x32_bf16(af0, bf1, acc[0][1], 0, 0, 0);
            acc[1][0] = __builtin_amdgcn_mfma_f32_16x16x32_bf16(af1, bf0, acc[1][0], 0, 0, 0);
            acc[1][1] = __builtin_amdgcn_mfma_f32_16x16x32_bf16(af1, bf1, acc[1][1], 0, 0, 0);
        }
    }

    // epilogue: bias + ELU + store + column stats
    const int r0 = m0 + wm + ((l >> 4) << 2);
    #pragma unroll
    for (int ni = 0; ni < 2; ++ni) {
        const int col = n0 + wn + ni * 16 + (l & 15);
        const float bias = b1[col];
        float s1 = 0.f, s2 = 0.f;
        #pragma unroll
        for (int mi = 0; mi < 2; ++mi) {
            #pragma unroll
            for (int rr = 0; rr < 4; ++rr) {
                float v = acc[mi][ni][rr] + bias;
                v = v > 0.f ? v : expm1f(v);
                h[(long)(r0 + mi * 16 + rr) * NE + col] = v;
                s1 += v; s2 += v * v;
            }
        }
        // lanes l, l^16, l^32, l^48 share col; reduce 32 rows of this wave
        s1 += __shfl_xor(s1, 16); s2 += __shfl_xor(s2, 16);
        s1 += __shfl_xor(s1, 32); s2 += __shfl_xor(s2, 32);
        if (l < 16) {
            unsafeAtomicAdd(&s1s2[col], s1);
            unsafeAtomicAdd(&s1s2[NE + col], s2);
        }
    }
}

// ---------------------------------------------------------------------------
// Kernel 3: fused finalize + output. Each block recomputes the folded BN/W2
// coefficients (4 KB read, L2-hot) then does 4 rows of the 512-dot product.
// ---------------------------------------------------------------------------
__global__ __launch_bounds__(256) void out_kernel(
    const float* __restrict__ h, const float* __restrict__ s1s2,
    const float* __restrict__ gamma, const float* __restrict__ beta,
    const float* __restrict__ W2, const float* __restrict__ b2,
    float* __restrict__ out)
{
    __shared__ float coef[NE];
    __shared__ float red[256];
    const int t = threadIdx.x;

    float term = 0.f;
    #pragma unroll
    for (int i = 0; i < 2; ++i) {
        const int e = t + i * 256;
        const float s1 = s1s2[e];
        const float s2 = s1s2[NE + e];
        const float mu = s1 * (1.0f / NB);
        const float var = s2 * (1.0f / NB) - mu * mu;
        const float rs = rsqrtf(var + 1e-5f);
        const float g = gamma[e], wv = W2[e];
        coef[e] = rs * g * wv;
        term += (beta[e] - mu * rs * g) * wv;
    }
    red[t] = term;
    __syncthreads();
    #pragma unroll
    for (int off = 128; off > 0; off >>= 1) {
        if (t < off) red[t] += red[t + off];
        __syncthreads();
    }
    const float cst = red[0] + b2[0];

    const int w = t >> 6;
    const int l = t & 63;
    const int row = blockIdx.x * 4 + w;
    const f32x4* h4 = (const f32x4*)(h + (long)row * NE);
    f32x4 x0 = h4[l * 2], x1 = h4[l * 2 + 1];
    f32x4 c0 = *(const f32x4*)&coef[l * 8];
    f32x4 c1 = *(const f32x4*)&coef[l * 8 + 4];
    float dot = x0.x * c0.x + x0.y * c0.y + x0.z * c0.z + x0.w * c0.w
              + x1.x * c1.x + x1.y * c1.y + x1.z * c1.z + x1.w * c1.w;
    #pragma unroll
    for (int off = 32; off > 0; off >>= 1) dot += __shfl_down(dot, off);
    if (l == 0) out[row] = dot + cst;
}

// ---------------------------------------------------------------------------
extern "C" void kernel_launch(void* const* d_in, const int* in_sizes, int n_in,
                              void* d_out, int out_size, void* d_ws, size_t ws_size,
                              hipStream_t stream)
{
    const float* q    = (const float*)d_in[0];
    const float* vq   = (const float*)d_in[1];
    const float* aa   = (const float*)d_in[2];
    const float* va   = (const float*)d_in[3];
    const float* W1   = (const float*)d_in[4];
    const float* b1   = (const float*)d_in[5];
    const float* gam  = (const float*)d_in[6];
    const float* bet  = (const float*)d_in[7];
    const float* W2   = (const float*)d_in[8];
    const float* b2   = (const float*)d_in[9];
    const int* qlen   = (const int*)d_in[10];
    const int* alen   = (const int*)d_in[11];
    float* out = (float*)d_out;

    char* ws = (char*)d_ws;
    unsigned short* feat = (unsigned short*)ws;                 // 20,971,520 B
    unsigned short* w1t  = (unsigned short*)(ws + 20971520);    //  5,242,880 B
    float* hbuf          = (float*)(ws + 26214400);             //  4,194,304 B
    float* s1s2          = (float*)(ws + 30408704);             //      4,096 B

    reduce_w1t_kernel<<<3072, 1024, 0, stream>>>(
        (const f32x4*)q, (const f32x4*)vq, (const f32x4*)aa, (const f32x4*)va,
        qlen, alen, (ushort4*)feat, W1, w1t, s1s2);

    gemm_kernel<<<256, 256, 0, stream>>>(feat, w1t, b1, hbuf, s1s2);

    out_kernel<<<512, 256, 0, stream>>>(hbuf, s1s2, gam, bet, W2, b2, out);
}